// Round 14
// baseline (44.511 us; speedup 1.0000x reference)
//
#include <hip/hip_runtime.h>
#include <math.h>

// OT_Loss3: batched Sinkhorn (B=8, N_PTS=1024, M=4096, REG=10).
// K = Ky (x) Kx separable; rank-4 via Taylor of exp(x*c/5).
// 8 blocks x 512 threads (2 points + 8 cells per thread), atomic-free
// phase combine: wave partials to RED[wv][brl], consumers sum 8 partials
// in fixed order (deterministic). 6 barriers. NITER=2.
// R13 lesson: hipcc pins 512-thr blocks to a 128-VGPR target regardless of
// launch_bounds' 2nd arg (64 VGPR at 1024-thr). So fit 128 by pressure
// reduction: Bx[4][8] (32 regs) -> exq[8] + inline power recompute, and
// stats phase reordered (wd first, then beta stats) to halve peak live.
// Folding (R6 lesson): gammas in POINT factors only; S core = RAW S6 low block.

#define NITER 2

__device__ __forceinline__ float rcpf(float x) {
    return __builtin_amdgcn_rcpf(x);   // ~1e-7 rel err, fine for Sinkhorn
}
__device__ __forceinline__ float gamf(int p) {
    return (p == 0) ? 1.0f : (p == 1) ? 0.2f : (p == 2) ? 0.02f : (1.0f/750.0f);
}
__device__ __forceinline__ void mk_folded(float x, float out[4]) {
    float e = expf(-0.1f*x*x);
    float x2 = x*x;
    out[0] = e;
    out[1] = 0.2f*e*x;
    out[2] = 0.02f*e*x2;
    out[3] = (1.0f/750.0f)*e*x2*x;
}
__device__ __forceinline__ void mk6(float x, float out[6]) {
    float e = expf(-0.1f*x*x);
    float pw = e;
    #pragma unroll
    for (int p = 0; p < 6; ++p) { out[p] = pw; pw *= x; }
}

// Split-butterfly: reduce 16 per-lane accumulators over 64 lanes.
// Lane's result = total sum of logical index bitrev4(lane&15).
__device__ __forceinline__ float reduce16(float acc[16], int lane) {
    #pragma unroll
    for (int s = 0; s < 4; ++s) {
        const int m = 1 << s;
        const int h = 8 >> s;          // 8,4,2,1
        const bool hi = (lane & m) != 0;
        #pragma unroll
        for (int k = 0; k < h; ++k) {
            float send = hi ? acc[k]     : acc[k+h];
            float keep = hi ? acc[k+h]   : acc[k];
            acc[k] = keep + __shfl_xor(send, m, 64);
        }
    }
    float r = acc[0];
    r += __shfl_xor(r, 16, 64);
    r += __shfl_xor(r, 32, 64);
    return r;
}

// Consumer-side combine: out[k] = sum over 8 wave partials (fixed order).
__device__ __forceinline__ void sum8(const float RED[][16], float out[16]) {
    float4 acc[4];
    #pragma unroll
    for (int j = 0; j < 4; ++j) acc[j] = *(const float4*)&RED[0][4*j];
    #pragma unroll
    for (int w = 1; w < 8; ++w) {
        #pragma unroll
        for (int j = 0; j < 4; ++j) {
            float4 tv = *(const float4*)&RED[w][4*j];
            acc[j].x += tv.x; acc[j].y += tv.y; acc[j].z += tv.z; acc[j].w += tv.w;
        }
    }
    #pragma unroll
    for (int j = 0; j < 4; ++j) {
        out[4*j+0]=acc[j].x; out[4*j+1]=acc[j].y;
        out[4*j+2]=acc[j].z; out[4*j+3]=acc[j].w;
    }
}

__device__ __forceinline__ float point_u(const float Sl[16], const float Ayg[4],
                                         const float Axg[4]) {
    float kv = 0.f;
    #pragma unroll
    for (int p = 0; p < 4; ++p) {
        float h = Sl[p*4+0]*Axg[0] + Sl[p*4+1]*Axg[1]
                + Sl[p*4+2]*Axg[2] + Sl[p*4+3]*Axg[3];
        kv += Ayg[p]*h;
    }
    return (1.0f/1024.0f)*rcpf(kv + 1e-16f);
}

// wd contribution of one point (R7-validated formula, verbatim).
// S4 = RAW S6 low block; EXT[a2*4+q]=S6[4+a2][q]; EXT[8+p*2+b']=S6[p][4+b'].
__device__ __forceinline__ float wd_point2(const float Axe[6], const float Aye[6],
                                           const float Axg[4], const float Ayg[4],
                                           float u, const float* __restrict__ S4,
                                           const float* __restrict__ EXT) {
    float adx[6], ady[6];
    #pragma unroll
    for (int b = 0; b < 6; ++b) {
        float vx = 0.f, vy = 0.f;
        if (b <= 3)           { vx += gamf(b)*Axe[b+2];        vy += gamf(b)*Aye[b+2]; }
        if (b >= 1 && b <= 4) { vx -= 2.0f*gamf(b-1)*Axe[b];   vy -= 2.0f*gamf(b-1)*Aye[b]; }
        if (b >= 2)           { vx += gamf(b-2)*Axe[b-2];      vy += gamf(b-2)*Aye[b-2]; }
        adx[b] = vx; ady[b] = vy;
    }
    float t1 = 0.f, t2 = 0.f;
    #pragma unroll
    for (int a = 0; a < 4; ++a) {
        float h1 = S4[a*4+0]*Axg[0] + S4[a*4+1]*Axg[1]
                 + S4[a*4+2]*Axg[2] + S4[a*4+3]*Axg[3];
        t1 += ady[a]*h1;
        float h2 = S4[a*4+0]*adx[0] + S4[a*4+1]*adx[1]
                 + S4[a*4+2]*adx[2] + S4[a*4+3]*adx[3]
                 + EXT[8+a*2+0]*adx[4] + EXT[8+a*2+1]*adx[5];
        t2 += Ayg[a]*h2;
    }
    #pragma unroll
    for (int a2 = 0; a2 < 2; ++a2) {
        float h1 = EXT[a2*4+0]*Axg[0] + EXT[a2*4+1]*Axg[1]
                 + EXT[a2*4+2]*Axg[2] + EXT[a2*4+3]*Axg[3];
        t1 += ady[4+a2]*h1;
    }
    return u*(t1 + t2);
}

__global__ __launch_bounds__(512, 1) void ot_main(
    const float* __restrict__ nd_g, const float* __restrict__ ud_g,
    const float* __restrict__ pts_g, const float* __restrict__ vp_g,
    float* __restrict__ ws, int* __restrict__ cnt, float* __restrict__ out)
{
    const int img = blockIdx.x;
    const int t = threadIdx.x;
    const int lane = t & 63;
    const int wv = t >> 6;                 // 8 waves

    const float* nd  = nd_g  + img*4096;
    const float* ud  = ud_g  + img*4096;
    const float* pts = pts_g + img*2048;
    const float* vp  = vp_g  + img*4096;

    // Per-wave partial stores; every entry written each use -> no zeroing.
    __shared__ __align__(16) float REDA[8][16];   // T partials (points phases)
    __shared__ __align__(16) float REDB[8][16];   // S partials (S0 + cells)
    __shared__ __align__(16) float REDC[8][16];   // EXT partials (last cells)
    __shared__ __align__(16) float REDD[8][12];   // final stats partials

    // ---- points setup (2 points/thread), gamma-folded rank-4 factors ----
    float2 pA = ((const float2*)pts)[t];
    float2 pB = ((const float2*)pts)[t + 512];
    const float xa = pA.x*(1.0f/256.0f)-1.0f, ya = pA.y*(1.0f/256.0f)-1.0f;
    const float xb = pB.x*(1.0f/256.0f)-1.0f, yb = pB.y*(1.0f/256.0f)-1.0f;
    float Axga[4], Ayga[4], Axgb[4], Aygb[4];
    mk_folded(xa, Axga); mk_folded(ya, Ayga);
    mk_folded(xb, Axgb); mk_folded(yb, Aygb);

    // ---- cells setup (8 cells/thread: row jy, cols jx0..jx0+7) ----
    // Pressure fix (R13): keep only exq[8]; powers ex*cx^p rebuilt inline.
    const int jy = t >> 3;
    const int jx0 = (t & 7) << 3;
    const float cy = (float)(8*jy + 4) * (1.0f/256.0f) - 1.0f;
    const float cx0 = (float)(8*jx0 + 4) * (1.0f/256.0f) - 1.0f;  // + i*0.03125
    float By[4];
    {
        float ey = expf(-0.1f*cy*cy);
        By[0]=ey; By[1]=ey*cy; By[2]=By[1]*cy; By[3]=By[2]*cy;
    }
    float exq[8];
    #pragma unroll
    for (int i = 0; i < 8; ++i) {
        float cx = cx0 + 0.03125f*(float)i;
        exq[i] = expf(-0.1f*cx*cx);
    }
    float br[8], vr[8];
    {
        float4 a = ((const float4*)nd)[2*t], b = ((const float4*)nd)[2*t+1];
        br[0]=a.x; br[1]=a.y; br[2]=a.z; br[3]=a.w;
        br[4]=b.x; br[5]=b.y; br[6]=b.z; br[7]=b.w;
        float4 c = ((const float4*)vp)[2*t], d = ((const float4*)vp)[2*t+1];
        vr[0]=c.x; vr[1]=c.y; vr[2]=c.z; vr[3]=c.w;
        vr[4]=d.x; vr[5]=d.y; vr[6]=d.z; vr[7]=d.w;
    }

    const int brl = ((lane&1)<<3) | ((lane&2)<<1) | ((lane&4)>>1) | ((lane&8)>>3);

    // ---- S0 from v0 = v_pred (write-don't-accumulate: no pre-barrier) ----
    {
        float wx[4] = {0.f,0.f,0.f,0.f};
        #pragma unroll
        for (int i = 0; i < 8; ++i) {
            float cx = cx0 + 0.03125f*(float)i;
            float b0 = exq[i], b1 = b0*cx, b2 = b1*cx, b3 = b2*cx;
            float w = vr[i];
            wx[0] += w*b0; wx[1] += w*b1; wx[2] += w*b2; wx[3] += w*b3;
        }
        float acc[16];
        #pragma unroll
        for (int p = 0; p < 4; ++p)
            #pragma unroll
            for (int q = 0; q < 4; ++q)
                acc[p*4+q] = By[p]*wx[q];
        float red = reduce16(acc, lane);
        if (lane < 16) REDB[wv][brl] = red;
    }
    __syncthreads();                                   // B1

    float ua = 0.f, ub = 0.f, upa = 0.f, upb = 0.f;

    #pragma unroll 1
    for (int it = 0; it < NITER; ++it) {
        // ---- POINTS: Sl = sum8(REDB); u; T partials -> REDA ----
        float Sl[16];
        sum8(REDB, Sl);

        ua = point_u(Sl, Ayga, Axga);
        ub = point_u(Sl, Aygb, Axgb);
        if (it == 0) { upa = ua; upb = ub; }   // u_pred = first-iteration u

        float acc[16];
        #pragma unroll
        for (int p = 0; p < 4; ++p) {
            float ca = ua*Ayga[p], cb = ub*Aygb[p];
            #pragma unroll
            for (int q = 0; q < 4; ++q)
                acc[p*4+q] = ca*Axga[q] + cb*Axgb[q];
        }
        float red = reduce16(acc, lane);
        if (lane < 16) REDA[wv][brl] = red;
        __syncthreads();                               // B2/B4

        // ---- CELLS: Tl = sum8(REDA); v; S partials -> REDB ----
        float Tl[16];
        sum8(REDA, Tl);

        float hy[4];
        #pragma unroll
        for (int q = 0; q < 4; ++q)
            hy[q] = Tl[0*4+q]*By[0] + Tl[1*4+q]*By[1]
                  + Tl[2*4+q]*By[2] + Tl[3*4+q]*By[3];

        float wx[4] = {0.f,0.f,0.f,0.f};
        #pragma unroll
        for (int i = 0; i < 8; ++i) {
            float cx = cx0 + 0.03125f*(float)i;
            float b0 = exq[i], b1 = b0*cx, b2 = b1*cx, b3 = b2*cx;
            float R = hy[0]*b0 + hy[1]*b1 + hy[2]*b2 + hy[3]*b3;
            float w = br[i]*rcpf(R + 1e-16f);
            vr[i] = w;
            wx[0] += w*b0; wx[1] += w*b1; wx[2] += w*b2; wx[3] += w*b3;
        }
        float acc2[16];
        #pragma unroll
        for (int p = 0; p < 4; ++p)
            #pragma unroll
            for (int q = 0; q < 4; ++q)
                acc2[p*4+q] = By[p]*wx[q];
        float red2 = reduce16(acc2, lane);
        if (lane < 16) REDB[wv][brl] = red2;

        if (it == NITER-1) {
            // fused EXT partials: raw S6 extension entries from final vr
            float By4 = By[3]*cy, By5 = By4*cy;
            float wx4 = 0.f, wx5 = 0.f;
            #pragma unroll
            for (int i = 0; i < 8; ++i) {
                float cx = cx0 + 0.03125f*(float)i;
                float cx2 = cx*cx;
                float b4 = exq[i]*cx2*cx2;          // ex*cx^4
                wx4 += vr[i]*b4; wx5 += vr[i]*b4*cx;
            }
            float acc3[16];
            #pragma unroll
            for (int q = 0; q < 4; ++q) { acc3[q] = By4*wx[q]; acc3[4+q] = By5*wx[q]; }
            #pragma unroll
            for (int p = 0; p < 4; ++p) { acc3[8+p*2] = By[p]*wx4; acc3[8+p*2+1] = By[p]*wx5; }
            float red3 = reduce16(acc3, lane);
            if (lane < 16) REDC[wv][brl] = red3;
        }
        __syncthreads();                               // B3/B5
    }

    // ---- stats phase, reordered for pressure: wd FIRST, then beta stats ----
    float part[10];
    {
        float SF[16], EXTs[16];
        sum8(REDB, SF);
        sum8(REDC, EXTs);

        float Axe[6], Aye[6];
        mk6(xa, Axe); mk6(ya, Aye);
        float wdp = wd_point2(Axe, Aye, Axga, Ayga, ua, SF, EXTs);
        mk6(xb, Axe); mk6(yb, Aye);
        wdp += wd_point2(Axe, Aye, Axgb, Aygb, ub, SF, EXTs);
        part[9] = wdp;
    }
    {
        float4 ua4 = ((const float4*)ud)[2*t], ub4 = ((const float4*)ud)[2*t+1];
        float udr[8] = {ua4.x,ua4.y,ua4.z,ua4.w, ub4.x,ub4.y,ub4.z,ub4.w};
        float4 va4 = ((const float4*)vp)[2*t], vb4 = ((const float4*)vp)[2*t+1];
        float vpr[8] = {va4.x,va4.y,va4.z,va4.w, vb4.x,vb4.y,vb4.z,vb4.w};
        float nb=0.f, sud=0.f, sudb=0.f, svpv=0.f, svpvp=0.f, svv=0.f;
        #pragma unroll
        for (int i = 0; i < 8; ++i) {
            float beta = 10.0f*logf(vr[i] + 1e-16f);
            nb    += br[i]*beta;
            sud   += udr[i];
            sudb  += udr[i]*beta;
            svpv  += vpr[i]*vr[i];
            svpvp += vpr[i]*vpr[i];
            svv   += vr[i]*vr[i];
        }
        part[0] = nb;    part[1] = sud;   part[2] = sudb;  part[3] = svpv;
        part[4] = svpvp; part[5] = svv;
        part[6] = upa*ua + upb*ub;
        part[7] = upa*upa + upb*upb;
        part[8] = ua*ua + ub*ub;
    }
    #pragma unroll
    for (int off = 32; off > 0; off >>= 1) {
        #pragma unroll
        for (int i = 0; i < 10; ++i) part[i] += __shfl_down(part[i], off);
    }
    if (lane == 0) {
        #pragma unroll
        for (int i = 0; i < 10; ++i) REDD[wv][i] = part[i];
    }
    __syncthreads();                                   // B6
    if (t == 0) {
        float P[10];
        #pragma unroll
        for (int i = 0; i < 10; ++i) {
            float s = 0.f;
            for (int w = 0; w < 8; ++w) s += REDD[w][i];
            P[i] = s;
        }
        float sc = P[1], Sbt = P[2];
        float denom = sc*sc + 1e-8f;
        float loss_pre = (sc/denom)*Sbt - (Sbt/denom)*sc;   // == sum(ud*im_grad) ~ 0
        float nvp = fmaxf(sqrtf(P[4]), 1e-8f);
        float nv  = fmaxf(sqrtf(P[5]), 1e-8f);
        float c1  = P[3]/(nvp*nv);
        float nup = fmaxf(sqrtf(P[7]), 1e-8f);
        float nu  = fmaxf(sqrtf(P[8]), 1e-8f);
        float c2  = P[6]/(nup*nu);
        float loss_i = loss_pre + (1.0f - c1) + (1.0f - c2);

        // publish partials (device-scope), last block sums -> d_out (R4-R13 proven)
        __hip_atomic_store(&ws[img*3 + 0], loss_i, __ATOMIC_RELAXED, __HIP_MEMORY_SCOPE_AGENT);
        __hip_atomic_store(&ws[img*3 + 1], P[9],   __ATOMIC_RELAXED, __HIP_MEMORY_SCOPE_AGENT);
        __hip_atomic_store(&ws[img*3 + 2], P[0],   __ATOMIC_RELAXED, __HIP_MEMORY_SCOPE_AGENT);
        int prev = __hip_atomic_fetch_add(cnt, 1, __ATOMIC_ACQ_REL, __HIP_MEMORY_SCOPE_AGENT);
        if (prev == 7) {                     // last block: deterministic fixed-order sum
            float s0=0.f, s1=0.f, s2=0.f;
            for (int i = 0; i < 8; ++i) {
                s0 += __hip_atomic_load(&ws[i*3+0], __ATOMIC_RELAXED, __HIP_MEMORY_SCOPE_AGENT);
                s1 += __hip_atomic_load(&ws[i*3+1], __ATOMIC_RELAXED, __HIP_MEMORY_SCOPE_AGENT);
                s2 += __hip_atomic_load(&ws[i*3+2], __ATOMIC_RELAXED, __HIP_MEMORY_SCOPE_AGENT);
            }
            out[0] = s0; out[1] = s1; out[2] = s2;
        }
    }
}

extern "C" void kernel_launch(void* const* d_in, const int* in_sizes, int n_in,
                              void* d_out, int out_size, void* d_ws, size_t ws_size,
                              hipStream_t stream) {
    const float* nd  = (const float*)d_in[0];
    const float* ud  = (const float*)d_in[1];
    const float* pts = (const float*)d_in[2];
    const float* vp  = (const float*)d_in[3];
    float* out = (float*)d_out;
    float* ws  = (float*)d_ws;                       // 24 floats of partials
    int*   cnt = (int*)((char*)d_ws + 256);          // completion counter

    hipMemsetAsync(cnt, 0, 4, stream);               // graph-safe memset node
    ot_main<<<dim3(8), dim3(512), 0, stream>>>(nd, ud, pts, vp, ws, cnt, out);
}

// Round 15
// 42.536 us; speedup vs baseline: 1.0464x; 1.0464x over previous
//
#include <hip/hip_runtime.h>
#include <math.h>

// OT_Loss3: batched Sinkhorn (B=8, N_PTS=1024, M=4096, REG=10).
// K = Ky (x) Kx separable; rank-4 via Taylor of exp(x*c/5).
// 8 blocks x 512 threads (2 points + 8 cells per thread), atomic-free
// phase combine: wave partials to RED[wv][brl], consumers sum 8 partials
// in fixed order (deterministic). NITER=2. 7 barriers.
// R14 lesson (localized via R5-vs-R12 diff): the spills live in the
// EPILOGUE -- holding SF[16]+EXTs[16] in registers through wd_point2
// blew the 128-VGPR cap (512-thr builds never exceed 128). Fix = R5's
// pattern: final S/EXT cores summed once into LDS (SFE[32]) and read
// from LDS inside wd_point2 (broadcast ds_reads, conflict-free).
// Folding (R6 lesson): gammas in POINT factors only; S core = RAW S6 low block.

#define NITER 2

__device__ __forceinline__ float rcpf(float x) {
    return __builtin_amdgcn_rcpf(x);   // ~1e-7 rel err, fine for Sinkhorn
}
__device__ __forceinline__ float gamf(int p) {
    return (p == 0) ? 1.0f : (p == 1) ? 0.2f : (p == 2) ? 0.02f : (1.0f/750.0f);
}
__device__ __forceinline__ void mk_folded(float x, float out[4]) {
    float e = expf(-0.1f*x*x);
    float x2 = x*x;
    out[0] = e;
    out[1] = 0.2f*e*x;
    out[2] = 0.02f*e*x2;
    out[3] = (1.0f/750.0f)*e*x2*x;
}
__device__ __forceinline__ void mk6(float x, float out[6]) {
    float e = expf(-0.1f*x*x);
    float pw = e;
    #pragma unroll
    for (int p = 0; p < 6; ++p) { out[p] = pw; pw *= x; }
}

// Split-butterfly: reduce 16 per-lane accumulators over 64 lanes.
// Lane's result = total sum of logical index bitrev4(lane&15).
__device__ __forceinline__ float reduce16(float acc[16], int lane) {
    #pragma unroll
    for (int s = 0; s < 4; ++s) {
        const int m = 1 << s;
        const int h = 8 >> s;          // 8,4,2,1
        const bool hi = (lane & m) != 0;
        #pragma unroll
        for (int k = 0; k < h; ++k) {
            float send = hi ? acc[k]     : acc[k+h];
            float keep = hi ? acc[k+h]   : acc[k];
            acc[k] = keep + __shfl_xor(send, m, 64);
        }
    }
    float r = acc[0];
    r += __shfl_xor(r, 16, 64);
    r += __shfl_xor(r, 32, 64);
    return r;
}

// Consumer-side combine: out[k] = sum over 8 wave partials (fixed order).
__device__ __forceinline__ void sum8(const float RED[][16], float out[16]) {
    float4 acc[4];
    #pragma unroll
    for (int j = 0; j < 4; ++j) acc[j] = *(const float4*)&RED[0][4*j];
    #pragma unroll
    for (int w = 1; w < 8; ++w) {
        #pragma unroll
        for (int j = 0; j < 4; ++j) {
            float4 tv = *(const float4*)&RED[w][4*j];
            acc[j].x += tv.x; acc[j].y += tv.y; acc[j].z += tv.z; acc[j].w += tv.w;
        }
    }
    #pragma unroll
    for (int j = 0; j < 4; ++j) {
        out[4*j+0]=acc[j].x; out[4*j+1]=acc[j].y;
        out[4*j+2]=acc[j].z; out[4*j+3]=acc[j].w;
    }
}

__device__ __forceinline__ float point_u(const float Sl[16], const float Ayg[4],
                                         const float Axg[4]) {
    float kv = 0.f;
    #pragma unroll
    for (int p = 0; p < 4; ++p) {
        float h = Sl[p*4+0]*Axg[0] + Sl[p*4+1]*Axg[1]
                + Sl[p*4+2]*Axg[2] + Sl[p*4+3]*Axg[3];
        kv += Ayg[p]*h;
    }
    return (1.0f/1024.0f)*rcpf(kv + 1e-16f);
}

// wd contribution of one point (R7-validated formula; S4/EXT now read from
// LDS pointers -- R5's proven low-pressure pattern).
// S4 = RAW S6 low block; EXT[a2*4+q]=S6[4+a2][q]; EXT[8+p*2+b']=S6[p][4+b'].
__device__ __forceinline__ float wd_point2(const float Axe[6], const float Aye[6],
                                           const float Axg[4], const float Ayg[4],
                                           float u, const float* __restrict__ S4,
                                           const float* __restrict__ EXT) {
    float adx[6], ady[6];
    #pragma unroll
    for (int b = 0; b < 6; ++b) {
        float vx = 0.f, vy = 0.f;
        if (b <= 3)           { vx += gamf(b)*Axe[b+2];        vy += gamf(b)*Aye[b+2]; }
        if (b >= 1 && b <= 4) { vx -= 2.0f*gamf(b-1)*Axe[b];   vy -= 2.0f*gamf(b-1)*Aye[b]; }
        if (b >= 2)           { vx += gamf(b-2)*Axe[b-2];      vy += gamf(b-2)*Aye[b-2]; }
        adx[b] = vx; ady[b] = vy;
    }
    float t1 = 0.f, t2 = 0.f;
    #pragma unroll
    for (int a = 0; a < 4; ++a) {
        float h1 = S4[a*4+0]*Axg[0] + S4[a*4+1]*Axg[1]
                 + S4[a*4+2]*Axg[2] + S4[a*4+3]*Axg[3];
        t1 += ady[a]*h1;
        float h2 = S4[a*4+0]*adx[0] + S4[a*4+1]*adx[1]
                 + S4[a*4+2]*adx[2] + S4[a*4+3]*adx[3]
                 + EXT[8+a*2+0]*adx[4] + EXT[8+a*2+1]*adx[5];
        t2 += Ayg[a]*h2;
    }
    #pragma unroll
    for (int a2 = 0; a2 < 2; ++a2) {
        float h1 = EXT[a2*4+0]*Axg[0] + EXT[a2*4+1]*Axg[1]
                 + EXT[a2*4+2]*Axg[2] + EXT[a2*4+3]*Axg[3];
        t1 += ady[4+a2]*h1;
    }
    return u*(t1 + t2);
}

__global__ __launch_bounds__(512, 1) void ot_main(
    const float* __restrict__ nd_g, const float* __restrict__ ud_g,
    const float* __restrict__ pts_g, const float* __restrict__ vp_g,
    float* __restrict__ ws, int* __restrict__ cnt, float* __restrict__ out)
{
    const int img = blockIdx.x;
    const int t = threadIdx.x;
    const int lane = t & 63;
    const int wv = t >> 6;                 // 8 waves

    const float* nd  = nd_g  + img*4096;
    const float* ud  = ud_g  + img*4096;
    const float* pts = pts_g + img*2048;
    const float* vp  = vp_g  + img*4096;

    // Per-wave partial stores; every entry written each use -> no zeroing.
    __shared__ __align__(16) float REDA[8][16];   // T partials (points phases)
    __shared__ __align__(16) float REDB[8][16];   // S partials (S0 + cells)
    __shared__ __align__(16) float REDC[8][16];   // EXT partials (last cells)
    __shared__ __align__(16) float REDD[8][12];   // final stats partials
    __shared__ __align__(16) float SFE[32];       // final S4 (0..15) + EXT (16..31)

    // ---- points setup (2 points/thread), gamma-folded rank-4 factors ----
    float2 pA = ((const float2*)pts)[t];
    float2 pB = ((const float2*)pts)[t + 512];
    const float xa = pA.x*(1.0f/256.0f)-1.0f, ya = pA.y*(1.0f/256.0f)-1.0f;
    const float xb = pB.x*(1.0f/256.0f)-1.0f, yb = pB.y*(1.0f/256.0f)-1.0f;
    float Axga[4], Ayga[4], Axgb[4], Aygb[4];
    mk_folded(xa, Axga); mk_folded(ya, Ayga);
    mk_folded(xb, Axgb); mk_folded(yb, Aygb);

    // ---- cells setup (8 cells/thread: row jy, cols jx0..jx0+7) ----
    const int jy = t >> 3;
    const int jx0 = (t & 7) << 3;
    const float cy = (float)(8*jy + 4) * (1.0f/256.0f) - 1.0f;
    const float cx0 = (float)(8*jx0 + 4) * (1.0f/256.0f) - 1.0f;  // + i*0.03125
    float By[4];
    {
        float ey = expf(-0.1f*cy*cy);
        By[0]=ey; By[1]=ey*cy; By[2]=By[1]*cy; By[3]=By[2]*cy;
    }
    float exq[8];
    #pragma unroll
    for (int i = 0; i < 8; ++i) {
        float cx = cx0 + 0.03125f*(float)i;
        exq[i] = expf(-0.1f*cx*cx);
    }
    float br[8], vr[8];
    {
        float4 a = ((const float4*)nd)[2*t], b = ((const float4*)nd)[2*t+1];
        br[0]=a.x; br[1]=a.y; br[2]=a.z; br[3]=a.w;
        br[4]=b.x; br[5]=b.y; br[6]=b.z; br[7]=b.w;
        float4 c = ((const float4*)vp)[2*t], d = ((const float4*)vp)[2*t+1];
        vr[0]=c.x; vr[1]=c.y; vr[2]=c.z; vr[3]=c.w;
        vr[4]=d.x; vr[5]=d.y; vr[6]=d.z; vr[7]=d.w;
    }

    const int brl = ((lane&1)<<3) | ((lane&2)<<1) | ((lane&4)>>1) | ((lane&8)>>3);

    // ---- S0 from v0 = v_pred (write-don't-accumulate: no pre-barrier) ----
    {
        float wx[4] = {0.f,0.f,0.f,0.f};
        #pragma unroll
        for (int i = 0; i < 8; ++i) {
            float cx = cx0 + 0.03125f*(float)i;
            float b0 = exq[i], b1 = b0*cx, b2 = b1*cx, b3 = b2*cx;
            float w = vr[i];
            wx[0] += w*b0; wx[1] += w*b1; wx[2] += w*b2; wx[3] += w*b3;
        }
        float acc[16];
        #pragma unroll
        for (int p = 0; p < 4; ++p)
            #pragma unroll
            for (int q = 0; q < 4; ++q)
                acc[p*4+q] = By[p]*wx[q];
        float red = reduce16(acc, lane);
        if (lane < 16) REDB[wv][brl] = red;
    }
    __syncthreads();                                   // B1

    float ua = 0.f, ub = 0.f, upa = 0.f, upb = 0.f;

    #pragma unroll 1
    for (int it = 0; it < NITER; ++it) {
        // ---- POINTS: Sl = sum8(REDB); u; T partials -> REDA ----
        float Sl[16];
        sum8(REDB, Sl);

        ua = point_u(Sl, Ayga, Axga);
        ub = point_u(Sl, Aygb, Axgb);
        if (it == 0) { upa = ua; upb = ub; }   // u_pred = first-iteration u

        float acc[16];
        #pragma unroll
        for (int p = 0; p < 4; ++p) {
            float ca = ua*Ayga[p], cb = ub*Aygb[p];
            #pragma unroll
            for (int q = 0; q < 4; ++q)
                acc[p*4+q] = ca*Axga[q] + cb*Axgb[q];
        }
        float red = reduce16(acc, lane);
        if (lane < 16) REDA[wv][brl] = red;
        __syncthreads();                               // B2/B4

        // ---- CELLS: Tl = sum8(REDA); v; S partials -> REDB ----
        float Tl[16];
        sum8(REDA, Tl);

        float hy[4];
        #pragma unroll
        for (int q = 0; q < 4; ++q)
            hy[q] = Tl[0*4+q]*By[0] + Tl[1*4+q]*By[1]
                  + Tl[2*4+q]*By[2] + Tl[3*4+q]*By[3];

        float wx[4] = {0.f,0.f,0.f,0.f};
        #pragma unroll
        for (int i = 0; i < 8; ++i) {
            float cx = cx0 + 0.03125f*(float)i;
            float b0 = exq[i], b1 = b0*cx, b2 = b1*cx, b3 = b2*cx;
            float R = hy[0]*b0 + hy[1]*b1 + hy[2]*b2 + hy[3]*b3;
            float w = br[i]*rcpf(R + 1e-16f);
            vr[i] = w;
            wx[0] += w*b0; wx[1] += w*b1; wx[2] += w*b2; wx[3] += w*b3;
        }
        float acc2[16];
        #pragma unroll
        for (int p = 0; p < 4; ++p)
            #pragma unroll
            for (int q = 0; q < 4; ++q)
                acc2[p*4+q] = By[p]*wx[q];
        float red2 = reduce16(acc2, lane);
        if (lane < 16) REDB[wv][brl] = red2;

        if (it == NITER-1) {
            // fused EXT partials: raw S6 extension entries from final vr
            float By4 = By[3]*cy, By5 = By4*cy;
            float wx4 = 0.f, wx5 = 0.f;
            #pragma unroll
            for (int i = 0; i < 8; ++i) {
                float cx = cx0 + 0.03125f*(float)i;
                float cx2 = cx*cx;
                float b4 = exq[i]*cx2*cx2;          // ex*cx^4
                wx4 += vr[i]*b4; wx5 += vr[i]*b4*cx;
            }
            float acc3[16];
            #pragma unroll
            for (int q = 0; q < 4; ++q) { acc3[q] = By4*wx[q]; acc3[4+q] = By5*wx[q]; }
            #pragma unroll
            for (int p = 0; p < 4; ++p) { acc3[8+p*2] = By[p]*wx4; acc3[8+p*2+1] = By[p]*wx5; }
            float red3 = reduce16(acc3, lane);
            if (lane < 16) REDC[wv][brl] = red3;
        }
        __syncthreads();                               // B3/B5
    }

    // ---- publish final cores to LDS (fixed order; deterministic) ----
    if (t < 16) {
        float s = REDB[0][t];
        #pragma unroll
        for (int w = 1; w < 8; ++w) s += REDB[w][t];
        SFE[t] = s;
    } else if (t < 32) {
        const int e = t - 16;
        float s = REDC[0][e];
        #pragma unroll
        for (int w = 1; w < 8; ++w) s += REDC[w][e];
        SFE[16 + e] = s;
    }
    __syncthreads();                                   // B6

    // ---- stats phase: wd reads S4/EXT from LDS (low pressure) ----
    float part[10];
    {
        float Axe[6], Aye[6];
        mk6(xa, Axe); mk6(ya, Aye);
        float wdp = wd_point2(Axe, Aye, Axga, Ayga, ua, &SFE[0], &SFE[16]);
        mk6(xb, Axe); mk6(yb, Aye);
        wdp += wd_point2(Axe, Aye, Axgb, Aygb, ub, &SFE[0], &SFE[16]);
        part[9] = wdp;
    }
    {
        float4 ua4 = ((const float4*)ud)[2*t], ub4 = ((const float4*)ud)[2*t+1];
        float udr[8] = {ua4.x,ua4.y,ua4.z,ua4.w, ub4.x,ub4.y,ub4.z,ub4.w};
        float4 va4 = ((const float4*)vp)[2*t], vb4 = ((const float4*)vp)[2*t+1];
        float vpr[8] = {va4.x,va4.y,va4.z,va4.w, vb4.x,vb4.y,vb4.z,vb4.w};
        float nb=0.f, sud=0.f, sudb=0.f, svpv=0.f, svpvp=0.f, svv=0.f;
        #pragma unroll
        for (int i = 0; i < 8; ++i) {
            float beta = 10.0f*logf(vr[i] + 1e-16f);
            nb    += br[i]*beta;
            sud   += udr[i];
            sudb  += udr[i]*beta;
            svpv  += vpr[i]*vr[i];
            svpvp += vpr[i]*vpr[i];
            svv   += vr[i]*vr[i];
        }
        part[0] = nb;    part[1] = sud;   part[2] = sudb;  part[3] = svpv;
        part[4] = svpvp; part[5] = svv;
        part[6] = upa*ua + upb*ub;
        part[7] = upa*upa + upb*upb;
        part[8] = ua*ua + ub*ub;
    }
    #pragma unroll
    for (int off = 32; off > 0; off >>= 1) {
        #pragma unroll
        for (int i = 0; i < 10; ++i) part[i] += __shfl_down(part[i], off);
    }
    if (lane == 0) {
        #pragma unroll
        for (int i = 0; i < 10; ++i) REDD[wv][i] = part[i];
    }
    __syncthreads();                                   // B7
    if (t == 0) {
        float P[10];
        #pragma unroll
        for (int i = 0; i < 10; ++i) {
            float s = 0.f;
            for (int w = 0; w < 8; ++w) s += REDD[w][i];
            P[i] = s;
        }
        float sc = P[1], Sbt = P[2];
        float denom = sc*sc + 1e-8f;
        float loss_pre = (sc/denom)*Sbt - (Sbt/denom)*sc;   // == sum(ud*im_grad) ~ 0
        float nvp = fmaxf(sqrtf(P[4]), 1e-8f);
        float nv  = fmaxf(sqrtf(P[5]), 1e-8f);
        float c1  = P[3]/(nvp*nv);
        float nup = fmaxf(sqrtf(P[7]), 1e-8f);
        float nu  = fmaxf(sqrtf(P[8]), 1e-8f);
        float c2  = P[6]/(nup*nu);
        float loss_i = loss_pre + (1.0f - c1) + (1.0f - c2);

        // publish partials (device-scope), last block sums -> d_out (R4-R14 proven)
        __hip_atomic_store(&ws[img*3 + 0], loss_i, __ATOMIC_RELAXED, __HIP_MEMORY_SCOPE_AGENT);
        __hip_atomic_store(&ws[img*3 + 1], P[9],   __ATOMIC_RELAXED, __HIP_MEMORY_SCOPE_AGENT);
        __hip_atomic_store(&ws[img*3 + 2], P[0],   __ATOMIC_RELAXED, __HIP_MEMORY_SCOPE_AGENT);
        int prev = __hip_atomic_fetch_add(cnt, 1, __ATOMIC_ACQ_REL, __HIP_MEMORY_SCOPE_AGENT);
        if (prev == 7) {                     // last block: deterministic fixed-order sum
            float s0=0.f, s1=0.f, s2=0.f;
            for (int i = 0; i < 8; ++i) {
                s0 += __hip_atomic_load(&ws[i*3+0], __ATOMIC_RELAXED, __HIP_MEMORY_SCOPE_AGENT);
                s1 += __hip_atomic_load(&ws[i*3+1], __ATOMIC_RELAXED, __HIP_MEMORY_SCOPE_AGENT);
                s2 += __hip_atomic_load(&ws[i*3+2], __ATOMIC_RELAXED, __HIP_MEMORY_SCOPE_AGENT);
            }
            out[0] = s0; out[1] = s1; out[2] = s2;
        }
    }
}

extern "C" void kernel_launch(void* const* d_in, const int* in_sizes, int n_in,
                              void* d_out, int out_size, void* d_ws, size_t ws_size,
                              hipStream_t stream) {
    const float* nd  = (const float*)d_in[0];
    const float* ud  = (const float*)d_in[1];
    const float* pts = (const float*)d_in[2];
    const float* vp  = (const float*)d_in[3];
    float* out = (float*)d_out;
    float* ws  = (float*)d_ws;                       // 24 floats of partials
    int*   cnt = (int*)((char*)d_ws + 256);          // completion counter

    hipMemsetAsync(cnt, 0, 4, stream);               // graph-safe memset node
    ot_main<<<dim3(8), dim3(512), 0, stream>>>(nd, ud, pts, vp, ws, cnt, out);
}

// Round 16
// 40.182 us; speedup vs baseline: 1.1077x; 1.0586x over previous
//
#include <hip/hip_runtime.h>
#include <math.h>

// OT_Loss3: batched Sinkhorn (B=8, N_PTS=1024, M=4096, REG=10).
// K = Ky (x) Kx separable; rank-4 via Taylor of exp(x*c/5).
// 8 blocks x 512 threads (2 points + 8 cells per thread), atomic-free
// phase combine; NITER=2; 7 barriers. R15 insight: marginal phase cost
// ~0.5us; kernel dominated by fixed chains at idle-DPM clock. This round
// rebalances tails: (1) ud/vp stashed to LDS at setup (ud's HBM latency
// overlaps setup chain; vp already in regs), (2) beta-stats parts[0..8]
// moved into the SFE-publish interval, (3) final phase = wd only.
// Folding (R6): gammas in POINT factors only; S core = RAW S6 low block.

#define NITER 2

__device__ __forceinline__ float rcpf(float x) {
    return __builtin_amdgcn_rcpf(x);   // ~1e-7 rel err, fine for Sinkhorn
}
__device__ __forceinline__ float gamf(int p) {
    return (p == 0) ? 1.0f : (p == 1) ? 0.2f : (p == 2) ? 0.02f : (1.0f/750.0f);
}
__device__ __forceinline__ void mk_folded(float x, float out[4]) {
    float e = expf(-0.1f*x*x);
    float x2 = x*x;
    out[0] = e;
    out[1] = 0.2f*e*x;
    out[2] = 0.02f*e*x2;
    out[3] = (1.0f/750.0f)*e*x2*x;
}
__device__ __forceinline__ void mk6(float x, float out[6]) {
    float e = expf(-0.1f*x*x);
    float pw = e;
    #pragma unroll
    for (int p = 0; p < 6; ++p) { out[p] = pw; pw *= x; }
}

// Split-butterfly: reduce 16 per-lane accumulators over 64 lanes.
// Lane's result = total sum of logical index bitrev4(lane&15).
__device__ __forceinline__ float reduce16(float acc[16], int lane) {
    #pragma unroll
    for (int s = 0; s < 4; ++s) {
        const int m = 1 << s;
        const int h = 8 >> s;          // 8,4,2,1
        const bool hi = (lane & m) != 0;
        #pragma unroll
        for (int k = 0; k < h; ++k) {
            float send = hi ? acc[k]     : acc[k+h];
            float keep = hi ? acc[k+h]   : acc[k];
            acc[k] = keep + __shfl_xor(send, m, 64);
        }
    }
    float r = acc[0];
    r += __shfl_xor(r, 16, 64);
    r += __shfl_xor(r, 32, 64);
    return r;
}

// Consumer-side combine: out[k] = sum over 8 wave partials (fixed order).
__device__ __forceinline__ void sum8(const float RED[][16], float out[16]) {
    float4 acc[4];
    #pragma unroll
    for (int j = 0; j < 4; ++j) acc[j] = *(const float4*)&RED[0][4*j];
    #pragma unroll
    for (int w = 1; w < 8; ++w) {
        #pragma unroll
        for (int j = 0; j < 4; ++j) {
            float4 tv = *(const float4*)&RED[w][4*j];
            acc[j].x += tv.x; acc[j].y += tv.y; acc[j].z += tv.z; acc[j].w += tv.w;
        }
    }
    #pragma unroll
    for (int j = 0; j < 4; ++j) {
        out[4*j+0]=acc[j].x; out[4*j+1]=acc[j].y;
        out[4*j+2]=acc[j].z; out[4*j+3]=acc[j].w;
    }
}

__device__ __forceinline__ float point_u(const float Sl[16], const float Ayg[4],
                                         const float Axg[4]) {
    float kv = 0.f;
    #pragma unroll
    for (int p = 0; p < 4; ++p) {
        float h = Sl[p*4+0]*Axg[0] + Sl[p*4+1]*Axg[1]
                + Sl[p*4+2]*Axg[2] + Sl[p*4+3]*Axg[3];
        kv += Ayg[p]*h;
    }
    return (1.0f/1024.0f)*rcpf(kv + 1e-16f);
}

// wd contribution of one point (R7-validated formula; S4/EXT read from LDS).
// S4 = RAW S6 low block; EXT[a2*4+q]=S6[4+a2][q]; EXT[8+p*2+b']=S6[p][4+b'].
__device__ __forceinline__ float wd_point2(const float Axe[6], const float Aye[6],
                                           const float Axg[4], const float Ayg[4],
                                           float u, const float* __restrict__ S4,
                                           const float* __restrict__ EXT) {
    float adx[6], ady[6];
    #pragma unroll
    for (int b = 0; b < 6; ++b) {
        float vx = 0.f, vy = 0.f;
        if (b <= 3)           { vx += gamf(b)*Axe[b+2];        vy += gamf(b)*Aye[b+2]; }
        if (b >= 1 && b <= 4) { vx -= 2.0f*gamf(b-1)*Axe[b];   vy -= 2.0f*gamf(b-1)*Aye[b]; }
        if (b >= 2)           { vx += gamf(b-2)*Axe[b-2];      vy += gamf(b-2)*Aye[b-2]; }
        adx[b] = vx; ady[b] = vy;
    }
    float t1 = 0.f, t2 = 0.f;
    #pragma unroll
    for (int a = 0; a < 4; ++a) {
        float h1 = S4[a*4+0]*Axg[0] + S4[a*4+1]*Axg[1]
                 + S4[a*4+2]*Axg[2] + S4[a*4+3]*Axg[3];
        t1 += ady[a]*h1;
        float h2 = S4[a*4+0]*adx[0] + S4[a*4+1]*adx[1]
                 + S4[a*4+2]*adx[2] + S4[a*4+3]*adx[3]
                 + EXT[8+a*2+0]*adx[4] + EXT[8+a*2+1]*adx[5];
        t2 += Ayg[a]*h2;
    }
    #pragma unroll
    for (int a2 = 0; a2 < 2; ++a2) {
        float h1 = EXT[a2*4+0]*Axg[0] + EXT[a2*4+1]*Axg[1]
                 + EXT[a2*4+2]*Axg[2] + EXT[a2*4+3]*Axg[3];
        t1 += ady[4+a2]*h1;
    }
    return u*(t1 + t2);
}

__global__ __launch_bounds__(512, 1) void ot_main(
    const float* __restrict__ nd_g, const float* __restrict__ ud_g,
    const float* __restrict__ pts_g, const float* __restrict__ vp_g,
    float* __restrict__ ws, int* __restrict__ cnt, float* __restrict__ out)
{
    const int img = blockIdx.x;
    const int t = threadIdx.x;
    const int lane = t & 63;
    const int wv = t >> 6;                 // 8 waves

    const float* nd  = nd_g  + img*4096;
    const float* ud  = ud_g  + img*4096;
    const float* pts = pts_g + img*2048;
    const float* vp  = vp_g  + img*4096;

    // Per-wave partial stores; every entry written each use -> no zeroing.
    __shared__ __align__(16) float REDA[8][16];   // T partials (points phases)
    __shared__ __align__(16) float REDB[8][16];   // S partials (S0 + cells)
    __shared__ __align__(16) float REDC[8][16];   // EXT partials (last cells)
    __shared__ __align__(16) float REDD[8][12];   // final stats partials
    __shared__ __align__(16) float SFE[32];       // final S4 (0..15) + EXT (16..31)
    __shared__ __align__(16) float4 UDS[1024];    // ud stash (16 KB)
    __shared__ __align__(16) float4 VPS[1024];    // vp stash (16 KB)

    // ---- points setup (2 points/thread), gamma-folded rank-4 factors ----
    float2 pA = ((const float2*)pts)[t];
    float2 pB = ((const float2*)pts)[t + 512];
    const float xa = pA.x*(1.0f/256.0f)-1.0f, ya = pA.y*(1.0f/256.0f)-1.0f;
    const float xb = pB.x*(1.0f/256.0f)-1.0f, yb = pB.y*(1.0f/256.0f)-1.0f;
    float Axga[4], Ayga[4], Axgb[4], Aygb[4];
    mk_folded(xa, Axga); mk_folded(ya, Ayga);
    mk_folded(xb, Axgb); mk_folded(yb, Aygb);

    // ---- cells setup (8 cells/thread: row jy, cols jx0..jx0+7) ----
    const int jy = t >> 3;
    const int jx0 = (t & 7) << 3;
    const float cy = (float)(8*jy + 4) * (1.0f/256.0f) - 1.0f;
    const float cx0 = (float)(8*jx0 + 4) * (1.0f/256.0f) - 1.0f;  // + i*0.03125
    float By[4];
    {
        float ey = expf(-0.1f*cy*cy);
        By[0]=ey; By[1]=ey*cy; By[2]=By[1]*cy; By[3]=By[2]*cy;
    }
    float exq[8];
    #pragma unroll
    for (int i = 0; i < 8; ++i) {
        float cx = cx0 + 0.03125f*(float)i;
        exq[i] = expf(-0.1f*cx*cx);
    }
    float br[8], vr[8];
    {
        float4 a = ((const float4*)nd)[2*t], b = ((const float4*)nd)[2*t+1];
        br[0]=a.x; br[1]=a.y; br[2]=a.z; br[3]=a.w;
        br[4]=b.x; br[5]=b.y; br[6]=b.z; br[7]=b.w;
        float4 c = ((const float4*)vp)[2*t], d = ((const float4*)vp)[2*t+1];
        vr[0]=c.x; vr[1]=c.y; vr[2]=c.z; vr[3]=c.w;
        vr[4]=d.x; vr[5]=d.y; vr[6]=d.z; vr[7]=d.w;
        VPS[2*t] = c; VPS[2*t+1] = d;             // vp stash (already loaded)
        UDS[2*t]   = ((const float4*)ud)[2*t];    // ud load moved to setup
        UDS[2*t+1] = ((const float4*)ud)[2*t+1];
    }

    const int brl = ((lane&1)<<3) | ((lane&2)<<1) | ((lane&4)>>1) | ((lane&8)>>3);

    // ---- S0 from v0 = v_pred (write-don't-accumulate: no pre-barrier) ----
    {
        float wx[4] = {0.f,0.f,0.f,0.f};
        #pragma unroll
        for (int i = 0; i < 8; ++i) {
            float cx = cx0 + 0.03125f*(float)i;
            float b0 = exq[i], b1 = b0*cx, b2 = b1*cx, b3 = b2*cx;
            float w = vr[i];
            wx[0] += w*b0; wx[1] += w*b1; wx[2] += w*b2; wx[3] += w*b3;
        }
        float acc[16];
        #pragma unroll
        for (int p = 0; p < 4; ++p)
            #pragma unroll
            for (int q = 0; q < 4; ++q)
                acc[p*4+q] = By[p]*wx[q];
        float red = reduce16(acc, lane);
        if (lane < 16) REDB[wv][brl] = red;
    }
    __syncthreads();                                   // B1

    float ua = 0.f, ub = 0.f, upa = 0.f, upb = 0.f;

    #pragma unroll 1
    for (int it = 0; it < NITER; ++it) {
        // ---- POINTS: Sl = sum8(REDB); u; T partials -> REDA ----
        float Sl[16];
        sum8(REDB, Sl);

        ua = point_u(Sl, Ayga, Axga);
        ub = point_u(Sl, Aygb, Axgb);
        if (it == 0) { upa = ua; upb = ub; }   // u_pred = first-iteration u

        float acc[16];
        #pragma unroll
        for (int p = 0; p < 4; ++p) {
            float ca = ua*Ayga[p], cb = ub*Aygb[p];
            #pragma unroll
            for (int q = 0; q < 4; ++q)
                acc[p*4+q] = ca*Axga[q] + cb*Axgb[q];
        }
        float red = reduce16(acc, lane);
        if (lane < 16) REDA[wv][brl] = red;
        __syncthreads();                               // B2/B4

        // ---- CELLS: Tl = sum8(REDA); v; S partials -> REDB ----
        float Tl[16];
        sum8(REDA, Tl);

        float hy[4];
        #pragma unroll
        for (int q = 0; q < 4; ++q)
            hy[q] = Tl[0*4+q]*By[0] + Tl[1*4+q]*By[1]
                  + Tl[2*4+q]*By[2] + Tl[3*4+q]*By[3];

        float wx[4] = {0.f,0.f,0.f,0.f};
        #pragma unroll
        for (int i = 0; i < 8; ++i) {
            float cx = cx0 + 0.03125f*(float)i;
            float b0 = exq[i], b1 = b0*cx, b2 = b1*cx, b3 = b2*cx;
            float R = hy[0]*b0 + hy[1]*b1 + hy[2]*b2 + hy[3]*b3;
            float w = br[i]*rcpf(R + 1e-16f);
            vr[i] = w;
            wx[0] += w*b0; wx[1] += w*b1; wx[2] += w*b2; wx[3] += w*b3;
        }
        float acc2[16];
        #pragma unroll
        for (int p = 0; p < 4; ++p)
            #pragma unroll
            for (int q = 0; q < 4; ++q)
                acc2[p*4+q] = By[p]*wx[q];
        float red2 = reduce16(acc2, lane);
        if (lane < 16) REDB[wv][brl] = red2;

        if (it == NITER-1) {
            // fused EXT partials: raw S6 extension entries from final vr
            float By4 = By[3]*cy, By5 = By4*cy;
            float wx4 = 0.f, wx5 = 0.f;
            #pragma unroll
            for (int i = 0; i < 8; ++i) {
                float cx = cx0 + 0.03125f*(float)i;
                float cx2 = cx*cx;
                float b4 = exq[i]*cx2*cx2;          // ex*cx^4
                wx4 += vr[i]*b4; wx5 += vr[i]*b4*cx;
            }
            float acc3[16];
            #pragma unroll
            for (int q = 0; q < 4; ++q) { acc3[q] = By4*wx[q]; acc3[4+q] = By5*wx[q]; }
            #pragma unroll
            for (int p = 0; p < 4; ++p) { acc3[8+p*2] = By[p]*wx4; acc3[8+p*2+1] = By[p]*wx5; }
            float red3 = reduce16(acc3, lane);
            if (lane < 16) REDC[wv][brl] = red3;
        }
        __syncthreads();                               // B3/B5
    }

    // ---- SFE interval: t<32 publish cores; ALL compute beta stats ----
    if (t < 16) {
        float s = REDB[0][t];
        #pragma unroll
        for (int w = 1; w < 8; ++w) s += REDB[w][t];
        SFE[t] = s;
    } else if (t < 32) {
        const int e = t - 16;
        float s = REDC[0][e];
        #pragma unroll
        for (int w = 1; w < 8; ++w) s += REDC[w][e];
        SFE[16 + e] = s;
    }
    {
        float4 ua4 = UDS[2*t], ub4 = UDS[2*t+1];
        float udr[8] = {ua4.x,ua4.y,ua4.z,ua4.w, ub4.x,ub4.y,ub4.z,ub4.w};
        float4 va4 = VPS[2*t], vb4 = VPS[2*t+1];
        float vpr[8] = {va4.x,va4.y,va4.z,va4.w, vb4.x,vb4.y,vb4.z,vb4.w};
        float nb=0.f, sud=0.f, sudb=0.f, svpv=0.f, svpvp=0.f, svv=0.f;
        #pragma unroll
        for (int i = 0; i < 8; ++i) {
            float beta = 10.0f*logf(vr[i] + 1e-16f);
            nb    += br[i]*beta;
            sud   += udr[i];
            sudb  += udr[i]*beta;
            svpv  += vpr[i]*vr[i];
            svpvp += vpr[i]*vpr[i];
            svv   += vr[i]*vr[i];
        }
        float part9[9];
        part9[0] = nb;    part9[1] = sud;   part9[2] = sudb;  part9[3] = svpv;
        part9[4] = svpvp; part9[5] = svv;
        part9[6] = upa*ua + upb*ub;
        part9[7] = upa*upa + upb*upb;
        part9[8] = ua*ua + ub*ub;
        #pragma unroll
        for (int off = 32; off > 0; off >>= 1) {
            #pragma unroll
            for (int i = 0; i < 9; ++i) part9[i] += __shfl_down(part9[i], off);
        }
        if (lane == 0) {
            #pragma unroll
            for (int i = 0; i < 9; ++i) REDD[wv][i] = part9[i];
        }
    }
    __syncthreads();                                   // B6

    // ---- wd phase: reads S4/EXT from LDS (low pressure) ----
    {
        float Axe[6], Aye[6];
        mk6(xa, Axe); mk6(ya, Aye);
        float wdp = wd_point2(Axe, Aye, Axga, Ayga, ua, &SFE[0], &SFE[16]);
        mk6(xb, Axe); mk6(yb, Aye);
        wdp += wd_point2(Axe, Aye, Axgb, Aygb, ub, &SFE[0], &SFE[16]);
        #pragma unroll
        for (int off = 32; off > 0; off >>= 1) wdp += __shfl_down(wdp, off);
        if (lane == 0) REDD[wv][9] = wdp;
    }
    __syncthreads();                                   // B7
    if (t == 0) {
        float P[10];
        #pragma unroll
        for (int i = 0; i < 10; ++i) {
            float s = 0.f;
            for (int w = 0; w < 8; ++w) s += REDD[w][i];
            P[i] = s;
        }
        float sc = P[1], Sbt = P[2];
        float denom = sc*sc + 1e-8f;
        float loss_pre = (sc/denom)*Sbt - (Sbt/denom)*sc;   // == sum(ud*im_grad) ~ 0
        float nvp = fmaxf(sqrtf(P[4]), 1e-8f);
        float nv  = fmaxf(sqrtf(P[5]), 1e-8f);
        float c1  = P[3]/(nvp*nv);
        float nup = fmaxf(sqrtf(P[7]), 1e-8f);
        float nu  = fmaxf(sqrtf(P[8]), 1e-8f);
        float c2  = P[6]/(nup*nu);
        float loss_i = loss_pre + (1.0f - c1) + (1.0f - c2);

        // publish partials (device-scope), last block sums -> d_out (R4-R15 proven)
        __hip_atomic_store(&ws[img*3 + 0], loss_i, __ATOMIC_RELAXED, __HIP_MEMORY_SCOPE_AGENT);
        __hip_atomic_store(&ws[img*3 + 1], P[9],   __ATOMIC_RELAXED, __HIP_MEMORY_SCOPE_AGENT);
        __hip_atomic_store(&ws[img*3 + 2], P[0],   __ATOMIC_RELAXED, __HIP_MEMORY_SCOPE_AGENT);
        int prev = __hip_atomic_fetch_add(cnt, 1, __ATOMIC_ACQ_REL, __HIP_MEMORY_SCOPE_AGENT);
        if (prev == 7) {                     // last block: deterministic fixed-order sum
            float s0=0.f, s1=0.f, s2=0.f;
            for (int i = 0; i < 8; ++i) {
                s0 += __hip_atomic_load(&ws[i*3+0], __ATOMIC_RELAXED, __HIP_MEMORY_SCOPE_AGENT);
                s1 += __hip_atomic_load(&ws[i*3+1], __ATOMIC_RELAXED, __HIP_MEMORY_SCOPE_AGENT);
                s2 += __hip_atomic_load(&ws[i*3+2], __ATOMIC_RELAXED, __HIP_MEMORY_SCOPE_AGENT);
            }
            out[0] = s0; out[1] = s1; out[2] = s2;
        }
    }
}

extern "C" void kernel_launch(void* const* d_in, const int* in_sizes, int n_in,
                              void* d_out, int out_size, void* d_ws, size_t ws_size,
                              hipStream_t stream) {
    const float* nd  = (const float*)d_in[0];
    const float* ud  = (const float*)d_in[1];
    const float* pts = (const float*)d_in[2];
    const float* vp  = (const float*)d_in[3];
    float* out = (float*)d_out;
    float* ws  = (float*)d_ws;                       // 24 floats of partials
    int*   cnt = (int*)((char*)d_ws + 256);          // completion counter

    hipMemsetAsync(cnt, 0, 4, stream);               // graph-safe memset node
    ot_main<<<dim3(8), dim3(512), 0, stream>>>(nd, ud, pts, vp, ws, cnt, out);
}

// Round 17
// 36.082 us; speedup vs baseline: 1.2336x; 1.1136x over previous
//
#include <hip/hip_runtime.h>
#include <math.h>

// OT_Loss3: batched Sinkhorn (B=8, N_PTS=1024, M=4096, REG=10).
// K = Ky (x) Kx separable; rank-4 via Taylor of exp(x*c/5).
// 8 blocks x 512 threads (2 points + 8 cells per thread). NITER=2.
// R16 analysis: latency/inst-count bound at idle clock (all pipes <2%).
// This round cuts ~30% of per-thread insts:
//  (1) core exchange back to R5's LDS-atomic scheme (1 ds_add/lane<16 +
//      zero-opposite-buffer) -- the R12 sum8 consumer cost ~720 insts/thread;
//  (2) __expf/__logf fast intrinsics (v_exp_f32/v_log_f32, ~1e-6 rel);
//  (3) stats+wd merged into one interval (wd reads cores from LDS).
// 7 barriers. Folding (R6): gammas in POINT factors only; S core = RAW S6.

#define NITER 2

__device__ __forceinline__ float rcpf(float x) {
    return __builtin_amdgcn_rcpf(x);   // ~1e-7 rel err, fine for Sinkhorn
}
__device__ __forceinline__ float gamf(int p) {
    return (p == 0) ? 1.0f : (p == 1) ? 0.2f : (p == 2) ? 0.02f : (1.0f/750.0f);
}
__device__ __forceinline__ void mk_folded(float x, float out[4]) {
    float e = __expf(-0.1f*x*x);
    float x2 = x*x;
    out[0] = e;
    out[1] = 0.2f*e*x;
    out[2] = 0.02f*e*x2;
    out[3] = (1.0f/750.0f)*e*x2*x;
}
__device__ __forceinline__ void mk6(float x, float out[6]) {
    float e = __expf(-0.1f*x*x);
    float pw = e;
    #pragma unroll
    for (int p = 0; p < 6; ++p) { out[p] = pw; pw *= x; }
}

// Split-butterfly: reduce 16 per-lane accumulators over 64 lanes.
// Lane's result = total sum of logical index bitrev4(lane&15).
__device__ __forceinline__ float reduce16(float acc[16], int lane) {
    #pragma unroll
    for (int s = 0; s < 4; ++s) {
        const int m = 1 << s;
        const int h = 8 >> s;          // 8,4,2,1
        const bool hi = (lane & m) != 0;
        #pragma unroll
        for (int k = 0; k < h; ++k) {
            float send = hi ? acc[k]     : acc[k+h];
            float keep = hi ? acc[k+h]   : acc[k];
            acc[k] = keep + __shfl_xor(send, m, 64);
        }
    }
    float r = acc[0];
    r += __shfl_xor(r, 16, 64);
    r += __shfl_xor(r, 32, 64);
    return r;
}

__device__ __forceinline__ void load16(const float* __restrict__ src, float dst[16]) {
    *(float4*)&dst[0]  = *(const float4*)&src[0];
    *(float4*)&dst[4]  = *(const float4*)&src[4];
    *(float4*)&dst[8]  = *(const float4*)&src[8];
    *(float4*)&dst[12] = *(const float4*)&src[12];
}

__device__ __forceinline__ float point_u(const float Sl[16], const float Ayg[4],
                                         const float Axg[4]) {
    float kv = 0.f;
    #pragma unroll
    for (int p = 0; p < 4; ++p) {
        float h = Sl[p*4+0]*Axg[0] + Sl[p*4+1]*Axg[1]
                + Sl[p*4+2]*Axg[2] + Sl[p*4+3]*Axg[3];
        kv += Ayg[p]*h;
    }
    return (1.0f/1024.0f)*rcpf(kv + 1e-16f);
}

// wd contribution of one point (R7-validated formula; S4/EXT read from LDS).
// S4 = RAW S6 low block; EXT[a2*4+q]=S6[4+a2][q]; EXT[8+p*2+b']=S6[p][4+b'].
__device__ __forceinline__ float wd_point2(const float Axe[6], const float Aye[6],
                                           const float Axg[4], const float Ayg[4],
                                           float u, const float* __restrict__ S4,
                                           const float* __restrict__ EXT) {
    float adx[6], ady[6];
    #pragma unroll
    for (int b = 0; b < 6; ++b) {
        float vx = 0.f, vy = 0.f;
        if (b <= 3)           { vx += gamf(b)*Axe[b+2];        vy += gamf(b)*Aye[b+2]; }
        if (b >= 1 && b <= 4) { vx -= 2.0f*gamf(b-1)*Axe[b];   vy -= 2.0f*gamf(b-1)*Aye[b]; }
        if (b >= 2)           { vx += gamf(b-2)*Axe[b-2];      vy += gamf(b-2)*Aye[b-2]; }
        adx[b] = vx; ady[b] = vy;
    }
    float t1 = 0.f, t2 = 0.f;
    #pragma unroll
    for (int a = 0; a < 4; ++a) {
        float h1 = S4[a*4+0]*Axg[0] + S4[a*4+1]*Axg[1]
                 + S4[a*4+2]*Axg[2] + S4[a*4+3]*Axg[3];
        t1 += ady[a]*h1;
        float h2 = S4[a*4+0]*adx[0] + S4[a*4+1]*adx[1]
                 + S4[a*4+2]*adx[2] + S4[a*4+3]*adx[3]
                 + EXT[8+a*2+0]*adx[4] + EXT[8+a*2+1]*adx[5];
        t2 += Ayg[a]*h2;
    }
    #pragma unroll
    for (int a2 = 0; a2 < 2; ++a2) {
        float h1 = EXT[a2*4+0]*Axg[0] + EXT[a2*4+1]*Axg[1]
                 + EXT[a2*4+2]*Axg[2] + EXT[a2*4+3]*Axg[3];
        t1 += ady[4+a2]*h1;
    }
    return u*(t1 + t2);
}

__global__ __launch_bounds__(512, 1) void ot_main(
    const float* __restrict__ nd_g, const float* __restrict__ ud_g,
    const float* __restrict__ pts_g, const float* __restrict__ vp_g,
    float* __restrict__ ws, int* __restrict__ cnt, float* __restrict__ out)
{
    const int img = blockIdx.x;
    const int t = threadIdx.x;
    const int lane = t & 63;
    const int wv = t >> 6;                 // 8 waves

    const float* nd  = nd_g  + img*4096;
    const float* ud  = ud_g  + img*4096;
    const float* pts = pts_g + img*2048;
    const float* vp  = vp_g  + img*4096;

    __shared__ __align__(16) float Sb[2][16];     // S core, double-buffered
    __shared__ __align__(16) float Tb[2][16];     // T core, double-buffered
    __shared__ __align__(16) float EXTb[16];      // raw S6 extension entries
    __shared__ __align__(16) float REDD[8][12];   // final stats partials
    __shared__ __align__(16) float4 UDS[1024];    // ud stash (16 KB)
    __shared__ __align__(16) float4 VPS[1024];    // vp stash (16 KB)

    if (t < 16) {
        Sb[0][t]=0.f; Sb[1][t]=0.f; Tb[0][t]=0.f; Tb[1][t]=0.f; EXTb[t]=0.f;
    }

    // ---- points setup (2 points/thread), gamma-folded rank-4 factors ----
    float2 pA = ((const float2*)pts)[t];
    float2 pB = ((const float2*)pts)[t + 512];
    const float xa = pA.x*(1.0f/256.0f)-1.0f, ya = pA.y*(1.0f/256.0f)-1.0f;
    const float xb = pB.x*(1.0f/256.0f)-1.0f, yb = pB.y*(1.0f/256.0f)-1.0f;
    float Axga[4], Ayga[4], Axgb[4], Aygb[4];
    mk_folded(xa, Axga); mk_folded(ya, Ayga);
    mk_folded(xb, Axgb); mk_folded(yb, Aygb);

    // ---- cells setup (8 cells/thread: row jy, cols jx0..jx0+7) ----
    const int jy = t >> 3;
    const int jx0 = (t & 7) << 3;
    const float cy = (float)(8*jy + 4) * (1.0f/256.0f) - 1.0f;
    const float cx0 = (float)(8*jx0 + 4) * (1.0f/256.0f) - 1.0f;  // + i*0.03125
    float By[4];
    {
        float ey = __expf(-0.1f*cy*cy);
        By[0]=ey; By[1]=ey*cy; By[2]=By[1]*cy; By[3]=By[2]*cy;
    }
    float exq[8];
    #pragma unroll
    for (int i = 0; i < 8; ++i) {
        float cx = cx0 + 0.03125f*(float)i;
        exq[i] = __expf(-0.1f*cx*cx);
    }
    float br[8], vr[8];
    {
        float4 a = ((const float4*)nd)[2*t], b = ((const float4*)nd)[2*t+1];
        br[0]=a.x; br[1]=a.y; br[2]=a.z; br[3]=a.w;
        br[4]=b.x; br[5]=b.y; br[6]=b.z; br[7]=b.w;
        float4 c = ((const float4*)vp)[2*t], d = ((const float4*)vp)[2*t+1];
        vr[0]=c.x; vr[1]=c.y; vr[2]=c.z; vr[3]=c.w;
        vr[4]=d.x; vr[5]=d.y; vr[6]=d.z; vr[7]=d.w;
        VPS[2*t] = c; VPS[2*t+1] = d;             // vp stash (already loaded)
        UDS[2*t]   = ((const float4*)ud)[2*t];    // ud load overlapped w/ setup
        UDS[2*t+1] = ((const float4*)ud)[2*t+1];
    }

    const int brl = ((lane&1)<<3) | ((lane&2)<<1) | ((lane&4)>>1) | ((lane&8)>>3);

    __syncthreads();                                   // Bz (zeroing done)

    // ---- S0 from v0 = v_pred ----
    {
        float wx[4] = {0.f,0.f,0.f,0.f};
        #pragma unroll
        for (int i = 0; i < 8; ++i) {
            float cx = cx0 + 0.03125f*(float)i;
            float b0 = exq[i], b1 = b0*cx, b2 = b1*cx, b3 = b2*cx;
            float w = vr[i];
            wx[0] += w*b0; wx[1] += w*b1; wx[2] += w*b2; wx[3] += w*b3;
        }
        float acc[16];
        #pragma unroll
        for (int p = 0; p < 4; ++p)
            #pragma unroll
            for (int q = 0; q < 4; ++q)
                acc[p*4+q] = By[p]*wx[q];
        float red = reduce16(acc, lane);
        if (lane < 16) atomicAdd(&Sb[0][brl], red);
    }
    __syncthreads();                                   // B1

    float ua = 0.f, ub = 0.f, upa = 0.f, upb = 0.f;

    #pragma unroll 1
    for (int it = 0; it < NITER; ++it) {
        const int pi = it & 1;

        // ---- POINTS: read Sb[pi]; u; T partials -> Tb[pi] (atomic) ----
        float Sl[16];
        load16(&Sb[pi][0], Sl);
        if (t < 16) Sb[pi^1][t] = 0.f;      // zero target of this iter's cells

        ua = point_u(Sl, Ayga, Axga);
        ub = point_u(Sl, Aygb, Axgb);
        if (it == 0) { upa = ua; upb = ub; }   // u_pred = first-iteration u

        float acc[16];
        #pragma unroll
        for (int p = 0; p < 4; ++p) {
            float ca = ua*Ayga[p], cb = ub*Aygb[p];
            #pragma unroll
            for (int q = 0; q < 4; ++q)
                acc[p*4+q] = ca*Axga[q] + cb*Axgb[q];
        }
        float red = reduce16(acc, lane);
        if (lane < 16) atomicAdd(&Tb[pi][brl], red);
        __syncthreads();                               // B2/B4

        // ---- CELLS: read Tb[pi]; v; S partials -> Sb[pi^1] (atomic) ----
        float Tl[16];
        load16(&Tb[pi][0], Tl);
        if (t < 16) Tb[pi^1][t] = 0.f;      // zero target of next iter's points

        float hy[4];
        #pragma unroll
        for (int q = 0; q < 4; ++q)
            hy[q] = Tl[0*4+q]*By[0] + Tl[1*4+q]*By[1]
                  + Tl[2*4+q]*By[2] + Tl[3*4+q]*By[3];

        float wx[4] = {0.f,0.f,0.f,0.f};
        #pragma unroll
        for (int i = 0; i < 8; ++i) {
            float cx = cx0 + 0.03125f*(float)i;
            float b0 = exq[i], b1 = b0*cx, b2 = b1*cx, b3 = b2*cx;
            float R = hy[0]*b0 + hy[1]*b1 + hy[2]*b2 + hy[3]*b3;
            float w = br[i]*rcpf(R + 1e-16f);
            vr[i] = w;
            wx[0] += w*b0; wx[1] += w*b1; wx[2] += w*b2; wx[3] += w*b3;
        }
        float acc2[16];
        #pragma unroll
        for (int p = 0; p < 4; ++p)
            #pragma unroll
            for (int q = 0; q < 4; ++q)
                acc2[p*4+q] = By[p]*wx[q];
        float red2 = reduce16(acc2, lane);
        if (lane < 16) atomicAdd(&Sb[pi^1][brl], red2);

        if (it == NITER-1) {
            // fused EXT partials: raw S6 extension entries from final vr
            float By4 = By[3]*cy, By5 = By4*cy;
            float wx4 = 0.f, wx5 = 0.f;
            #pragma unroll
            for (int i = 0; i < 8; ++i) {
                float cx = cx0 + 0.03125f*(float)i;
                float cx2 = cx*cx;
                float b4 = exq[i]*cx2*cx2;          // ex*cx^4
                wx4 += vr[i]*b4; wx5 += vr[i]*b4*cx;
            }
            float acc3[16];
            #pragma unroll
            for (int q = 0; q < 4; ++q) { acc3[q] = By4*wx[q]; acc3[4+q] = By5*wx[q]; }
            #pragma unroll
            for (int p = 0; p < 4; ++p) { acc3[8+p*2] = By[p]*wx4; acc3[8+p*2+1] = By[p]*wx5; }
            float red3 = reduce16(acc3, lane);
            if (lane < 16) atomicAdd(&EXTb[brl], red3);
        }
        __syncthreads();                               // B3/B5
    }
    // Final raw S core lives in Sb[SFINAL]; EXTb complete.
    const int SFINAL = ((NITER-1)&1)^1;

    // ---- merged stats + wd interval (wd reads cores from LDS) ----
    float part[10];
    {
        float Axe[6], Aye[6];
        mk6(xa, Axe); mk6(ya, Aye);
        float wdp = wd_point2(Axe, Aye, Axga, Ayga, ua, &Sb[SFINAL][0], EXTb);
        mk6(xb, Axe); mk6(yb, Aye);
        wdp += wd_point2(Axe, Aye, Axgb, Aygb, ub, &Sb[SFINAL][0], EXTb);
        part[9] = wdp;
    }
    {
        float4 ua4 = UDS[2*t], ub4 = UDS[2*t+1];
        float udr[8] = {ua4.x,ua4.y,ua4.z,ua4.w, ub4.x,ub4.y,ub4.z,ub4.w};
        float4 va4 = VPS[2*t], vb4 = VPS[2*t+1];
        float vpr[8] = {va4.x,va4.y,va4.z,va4.w, vb4.x,vb4.y,vb4.z,vb4.w};
        float nb=0.f, sud=0.f, sudb=0.f, svpv=0.f, svpvp=0.f, svv=0.f;
        #pragma unroll
        for (int i = 0; i < 8; ++i) {
            float beta = 10.0f*__logf(vr[i] + 1e-16f);
            nb    += br[i]*beta;
            sud   += udr[i];
            sudb  += udr[i]*beta;
            svpv  += vpr[i]*vr[i];
            svpvp += vpr[i]*vpr[i];
            svv   += vr[i]*vr[i];
        }
        part[0] = nb;    part[1] = sud;   part[2] = sudb;  part[3] = svpv;
        part[4] = svpvp; part[5] = svv;
        part[6] = upa*ua + upb*ub;
        part[7] = upa*upa + upb*upb;
        part[8] = ua*ua + ub*ub;
    }
    #pragma unroll
    for (int off = 32; off > 0; off >>= 1) {
        #pragma unroll
        for (int i = 0; i < 10; ++i) part[i] += __shfl_down(part[i], off);
    }
    if (lane == 0) {
        #pragma unroll
        for (int i = 0; i < 10; ++i) REDD[wv][i] = part[i];
    }
    __syncthreads();                                   // B6
    if (t == 0) {
        float P[10];
        #pragma unroll
        for (int i = 0; i < 10; ++i) {
            float s = 0.f;
            for (int w = 0; w < 8; ++w) s += REDD[w][i];
            P[i] = s;
        }
        float sc = P[1], Sbt = P[2];
        float denom = sc*sc + 1e-8f;
        float loss_pre = (sc/denom)*Sbt - (Sbt/denom)*sc;   // == sum(ud*im_grad) ~ 0
        float nvp = fmaxf(sqrtf(P[4]), 1e-8f);
        float nv  = fmaxf(sqrtf(P[5]), 1e-8f);
        float c1  = P[3]/(nvp*nv);
        float nup = fmaxf(sqrtf(P[7]), 1e-8f);
        float nu  = fmaxf(sqrtf(P[8]), 1e-8f);
        float c2  = P[6]/(nup*nu);
        float loss_i = loss_pre + (1.0f - c1) + (1.0f - c2);

        // publish partials (device-scope), last block sums -> d_out (R4-R16 proven)
        __hip_atomic_store(&ws[img*3 + 0], loss_i, __ATOMIC_RELAXED, __HIP_MEMORY_SCOPE_AGENT);
        __hip_atomic_store(&ws[img*3 + 1], P[9],   __ATOMIC_RELAXED, __HIP_MEMORY_SCOPE_AGENT);
        __hip_atomic_store(&ws[img*3 + 2], P[0],   __ATOMIC_RELAXED, __HIP_MEMORY_SCOPE_AGENT);
        int prev = __hip_atomic_fetch_add(cnt, 1, __ATOMIC_ACQ_REL, __HIP_MEMORY_SCOPE_AGENT);
        if (prev == 7) {                     // last block: deterministic fixed-order sum
            float s0=0.f, s1=0.f, s2=0.f;
            for (int i = 0; i < 8; ++i) {
                s0 += __hip_atomic_load(&ws[i*3+0], __ATOMIC_RELAXED, __HIP_MEMORY_SCOPE_AGENT);
                s1 += __hip_atomic_load(&ws[i*3+1], __ATOMIC_RELAXED, __HIP_MEMORY_SCOPE_AGENT);
                s2 += __hip_atomic_load(&ws[i*3+2], __ATOMIC_RELAXED, __HIP_MEMORY_SCOPE_AGENT);
            }
            out[0] = s0; out[1] = s1; out[2] = s2;
        }
    }
}

extern "C" void kernel_launch(void* const* d_in, const int* in_sizes, int n_in,
                              void* d_out, int out_size, void* d_ws, size_t ws_size,
                              hipStream_t stream) {
    const float* nd  = (const float*)d_in[0];
    const float* ud  = (const float*)d_in[1];
    const float* pts = (const float*)d_in[2];
    const float* vp  = (const float*)d_in[3];
    float* out = (float*)d_out;
    float* ws  = (float*)d_ws;                       // 24 floats of partials
    int*   cnt = (int*)((char*)d_ws + 256);          // completion counter

    hipMemsetAsync(cnt, 0, 4, stream);               // graph-safe memset node
    ot_main<<<dim3(8), dim3(512), 0, stream>>>(nd, ud, pts, vp, ws, cnt, out);
}

// Round 18
// 35.536 us; speedup vs baseline: 1.2525x; 1.0154x over previous
//
#include <hip/hip_runtime.h>
#include <math.h>

// OT_Loss3: batched Sinkhorn (B=8, N_PTS=1024, M=4096, REG=10).
// K = Ky (x) Kx separable; rank-4 via Taylor of exp(x*c/5).
// 8 blocks x 512 threads (2 points + 8 cells per thread). NITER=2. 6 barriers.
// R18 changes: (1) cross-block combine = 3 global atomicAdds into d_out
// (graph memset re-zeros d_out each replay; fp-ordering jitter ~1e-6 <<
// 0.31 threshold) -- deletes cnt/fetch_add/last-block serial tail;
// (2) Bz barrier removed: S0 uses write-don't-accumulate partials (SP) +
// one sum8 in pts1; Tb[0]/EXTb zeroed inside the S0 interval; Sb/Tb
// rotation zeroing unchanged from R17 (proven).
// Folding (R6): gammas in POINT factors only; S core = RAW S6 low block.

#define NITER 2

__device__ __forceinline__ float rcpf(float x) {
    return __builtin_amdgcn_rcpf(x);   // ~1e-7 rel err, fine for Sinkhorn
}
__device__ __forceinline__ float gamf(int p) {
    return (p == 0) ? 1.0f : (p == 1) ? 0.2f : (p == 2) ? 0.02f : (1.0f/750.0f);
}
__device__ __forceinline__ void mk_folded(float x, float out[4]) {
    float e = __expf(-0.1f*x*x);
    float x2 = x*x;
    out[0] = e;
    out[1] = 0.2f*e*x;
    out[2] = 0.02f*e*x2;
    out[3] = (1.0f/750.0f)*e*x2*x;
}
__device__ __forceinline__ void mk6(float x, float out[6]) {
    float e = __expf(-0.1f*x*x);
    float pw = e;
    #pragma unroll
    for (int p = 0; p < 6; ++p) { out[p] = pw; pw *= x; }
}

// Split-butterfly: reduce 16 per-lane accumulators over 64 lanes.
// Lane's result = total sum of logical index bitrev4(lane&15).
__device__ __forceinline__ float reduce16(float acc[16], int lane) {
    #pragma unroll
    for (int s = 0; s < 4; ++s) {
        const int m = 1 << s;
        const int h = 8 >> s;          // 8,4,2,1
        const bool hi = (lane & m) != 0;
        #pragma unroll
        for (int k = 0; k < h; ++k) {
            float send = hi ? acc[k]     : acc[k+h];
            float keep = hi ? acc[k+h]   : acc[k];
            acc[k] = keep + __shfl_xor(send, m, 64);
        }
    }
    float r = acc[0];
    r += __shfl_xor(r, 16, 64);
    r += __shfl_xor(r, 32, 64);
    return r;
}

// Consumer-side combine: out[k] = sum over 8 wave partials (fixed order).
__device__ __forceinline__ void sum8(const float RED[][16], float out[16]) {
    float4 acc[4];
    #pragma unroll
    for (int j = 0; j < 4; ++j) acc[j] = *(const float4*)&RED[0][4*j];
    #pragma unroll
    for (int w = 1; w < 8; ++w) {
        #pragma unroll
        for (int j = 0; j < 4; ++j) {
            float4 tv = *(const float4*)&RED[w][4*j];
            acc[j].x += tv.x; acc[j].y += tv.y; acc[j].z += tv.z; acc[j].w += tv.w;
        }
    }
    #pragma unroll
    for (int j = 0; j < 4; ++j) {
        out[4*j+0]=acc[j].x; out[4*j+1]=acc[j].y;
        out[4*j+2]=acc[j].z; out[4*j+3]=acc[j].w;
    }
}

__device__ __forceinline__ void load16(const float* __restrict__ src, float dst[16]) {
    *(float4*)&dst[0]  = *(const float4*)&src[0];
    *(float4*)&dst[4]  = *(const float4*)&src[4];
    *(float4*)&dst[8]  = *(const float4*)&src[8];
    *(float4*)&dst[12] = *(const float4*)&src[12];
}

__device__ __forceinline__ float point_u(const float Sl[16], const float Ayg[4],
                                         const float Axg[4]) {
    float kv = 0.f;
    #pragma unroll
    for (int p = 0; p < 4; ++p) {
        float h = Sl[p*4+0]*Axg[0] + Sl[p*4+1]*Axg[1]
                + Sl[p*4+2]*Axg[2] + Sl[p*4+3]*Axg[3];
        kv += Ayg[p]*h;
    }
    return (1.0f/1024.0f)*rcpf(kv + 1e-16f);
}

// wd contribution of one point (R7-validated formula; S4/EXT read from LDS).
// S4 = RAW S6 low block; EXT[a2*4+q]=S6[4+a2][q]; EXT[8+p*2+b']=S6[p][4+b'].
__device__ __forceinline__ float wd_point2(const float Axe[6], const float Aye[6],
                                           const float Axg[4], const float Ayg[4],
                                           float u, const float* __restrict__ S4,
                                           const float* __restrict__ EXT) {
    float adx[6], ady[6];
    #pragma unroll
    for (int b = 0; b < 6; ++b) {
        float vx = 0.f, vy = 0.f;
        if (b <= 3)           { vx += gamf(b)*Axe[b+2];        vy += gamf(b)*Aye[b+2]; }
        if (b >= 1 && b <= 4) { vx -= 2.0f*gamf(b-1)*Axe[b];   vy -= 2.0f*gamf(b-1)*Aye[b]; }
        if (b >= 2)           { vx += gamf(b-2)*Axe[b-2];      vy += gamf(b-2)*Aye[b-2]; }
        adx[b] = vx; ady[b] = vy;
    }
    float t1 = 0.f, t2 = 0.f;
    #pragma unroll
    for (int a = 0; a < 4; ++a) {
        float h1 = S4[a*4+0]*Axg[0] + S4[a*4+1]*Axg[1]
                 + S4[a*4+2]*Axg[2] + S4[a*4+3]*Axg[3];
        t1 += ady[a]*h1;
        float h2 = S4[a*4+0]*adx[0] + S4[a*4+1]*adx[1]
                 + S4[a*4+2]*adx[2] + S4[a*4+3]*adx[3]
                 + EXT[8+a*2+0]*adx[4] + EXT[8+a*2+1]*adx[5];
        t2 += Ayg[a]*h2;
    }
    #pragma unroll
    for (int a2 = 0; a2 < 2; ++a2) {
        float h1 = EXT[a2*4+0]*Axg[0] + EXT[a2*4+1]*Axg[1]
                 + EXT[a2*4+2]*Axg[2] + EXT[a2*4+3]*Axg[3];
        t1 += ady[4+a2]*h1;
    }
    return u*(t1 + t2);
}

__global__ __launch_bounds__(512, 1) void ot_main(
    const float* __restrict__ nd_g, const float* __restrict__ ud_g,
    const float* __restrict__ pts_g, const float* __restrict__ vp_g,
    float* __restrict__ out)
{
    const int img = blockIdx.x;
    const int t = threadIdx.x;
    const int lane = t & 63;
    const int wv = t >> 6;                 // 8 waves

    const float* nd  = nd_g  + img*4096;
    const float* ud  = ud_g  + img*4096;
    const float* pts = pts_g + img*2048;
    const float* vp  = vp_g  + img*4096;

    __shared__ __align__(16) float SP[8][16];     // S0 per-wave partials
    __shared__ __align__(16) float Sb[2][16];     // S core, double-buffered
    __shared__ __align__(16) float Tb[2][16];     // T core, double-buffered
    __shared__ __align__(16) float EXTb[16];      // raw S6 extension entries
    __shared__ __align__(16) float REDD[8][12];   // final stats partials
    __shared__ __align__(16) float4 UDS[1024];    // ud stash (16 KB)
    __shared__ __align__(16) float4 VPS[1024];    // vp stash (16 KB)

    // ---- points setup (2 points/thread), gamma-folded rank-4 factors ----
    float2 pA = ((const float2*)pts)[t];
    float2 pB = ((const float2*)pts)[t + 512];
    const float xa = pA.x*(1.0f/256.0f)-1.0f, ya = pA.y*(1.0f/256.0f)-1.0f;
    const float xb = pB.x*(1.0f/256.0f)-1.0f, yb = pB.y*(1.0f/256.0f)-1.0f;
    float Axga[4], Ayga[4], Axgb[4], Aygb[4];
    mk_folded(xa, Axga); mk_folded(ya, Ayga);
    mk_folded(xb, Axgb); mk_folded(yb, Aygb);

    // ---- cells setup (8 cells/thread: row jy, cols jx0..jx0+7) ----
    const int jy = t >> 3;
    const int jx0 = (t & 7) << 3;
    const float cy = (float)(8*jy + 4) * (1.0f/256.0f) - 1.0f;
    const float cx0 = (float)(8*jx0 + 4) * (1.0f/256.0f) - 1.0f;  // + i*0.03125
    float By[4];
    {
        float ey = __expf(-0.1f*cy*cy);
        By[0]=ey; By[1]=ey*cy; By[2]=By[1]*cy; By[3]=By[2]*cy;
    }
    float exq[8];
    #pragma unroll
    for (int i = 0; i < 8; ++i) {
        float cx = cx0 + 0.03125f*(float)i;
        exq[i] = __expf(-0.1f*cx*cx);
    }
    float br[8], vr[8];
    {
        float4 a = ((const float4*)nd)[2*t], b = ((const float4*)nd)[2*t+1];
        br[0]=a.x; br[1]=a.y; br[2]=a.z; br[3]=a.w;
        br[4]=b.x; br[5]=b.y; br[6]=b.z; br[7]=b.w;
        float4 c = ((const float4*)vp)[2*t], d = ((const float4*)vp)[2*t+1];
        vr[0]=c.x; vr[1]=c.y; vr[2]=c.z; vr[3]=c.w;
        vr[4]=d.x; vr[5]=d.y; vr[6]=d.z; vr[7]=d.w;
        VPS[2*t] = c; VPS[2*t+1] = d;             // vp stash (already loaded)
        UDS[2*t]   = ((const float4*)ud)[2*t];    // ud load overlapped w/ setup
        UDS[2*t+1] = ((const float4*)ud)[2*t+1];
    }

    const int brl = ((lane&1)<<3) | ((lane&2)<<1) | ((lane&4)>>1) | ((lane&8)>>3);

    // ---- S0 interval: per-wave partials to SP (no atomics, no pre-zero);
    //      Tb[0]/EXTb zeroed here (disjoint addresses, used only after B1) ----
    if (t < 16) Tb[0][t] = 0.f;
    else if (t < 32) EXTb[t-16] = 0.f;
    {
        float wx[4] = {0.f,0.f,0.f,0.f};
        #pragma unroll
        for (int i = 0; i < 8; ++i) {
            float cx = cx0 + 0.03125f*(float)i;
            float b0 = exq[i], b1 = b0*cx, b2 = b1*cx, b3 = b2*cx;
            float w = vr[i];
            wx[0] += w*b0; wx[1] += w*b1; wx[2] += w*b2; wx[3] += w*b3;
        }
        float acc[16];
        #pragma unroll
        for (int p = 0; p < 4; ++p)
            #pragma unroll
            for (int q = 0; q < 4; ++q)
                acc[p*4+q] = By[p]*wx[q];
        float red = reduce16(acc, lane);
        if (lane < 16) SP[wv][brl] = red;
    }
    __syncthreads();                                   // B1

    float ua = 0.f, ub = 0.f, upa = 0.f, upb = 0.f;

    #pragma unroll 1
    for (int it = 0; it < NITER; ++it) {
        const int pi = it & 1;

        // ---- POINTS: read S core; u; T partials -> Tb[pi] (atomic) ----
        float Sl[16];
        if (it == 0) sum8(SP, Sl);          // S0 from write-partials
        else         load16(&Sb[pi][0], Sl);
        if (t < 16) Sb[pi^1][t] = 0.f;      // zero target of this iter's cells

        ua = point_u(Sl, Ayga, Axga);
        ub = point_u(Sl, Aygb, Axgb);
        if (it == 0) { upa = ua; upb = ub; }   // u_pred = first-iteration u

        float acc[16];
        #pragma unroll
        for (int p = 0; p < 4; ++p) {
            float ca = ua*Ayga[p], cb = ub*Aygb[p];
            #pragma unroll
            for (int q = 0; q < 4; ++q)
                acc[p*4+q] = ca*Axga[q] + cb*Axgb[q];
        }
        float red = reduce16(acc, lane);
        if (lane < 16) atomicAdd(&Tb[pi][brl], red);
        __syncthreads();                               // B2/B4

        // ---- CELLS: read Tb[pi]; v; S partials -> Sb[pi^1] (atomic) ----
        float Tl[16];
        load16(&Tb[pi][0], Tl);
        if (t < 16) Tb[pi^1][t] = 0.f;      // zero target of next iter's points

        float hy[4];
        #pragma unroll
        for (int q = 0; q < 4; ++q)
            hy[q] = Tl[0*4+q]*By[0] + Tl[1*4+q]*By[1]
                  + Tl[2*4+q]*By[2] + Tl[3*4+q]*By[3];

        float wx[4] = {0.f,0.f,0.f,0.f};
        #pragma unroll
        for (int i = 0; i < 8; ++i) {
            float cx = cx0 + 0.03125f*(float)i;
            float b0 = exq[i], b1 = b0*cx, b2 = b1*cx, b3 = b2*cx;
            float R = hy[0]*b0 + hy[1]*b1 + hy[2]*b2 + hy[3]*b3;
            float w = br[i]*rcpf(R + 1e-16f);
            vr[i] = w;
            wx[0] += w*b0; wx[1] += w*b1; wx[2] += w*b2; wx[3] += w*b3;
        }
        float acc2[16];
        #pragma unroll
        for (int p = 0; p < 4; ++p)
            #pragma unroll
            for (int q = 0; q < 4; ++q)
                acc2[p*4+q] = By[p]*wx[q];
        float red2 = reduce16(acc2, lane);
        if (lane < 16) atomicAdd(&Sb[pi^1][brl], red2);

        if (it == NITER-1) {
            // fused EXT partials: raw S6 extension entries from final vr
            float By4 = By[3]*cy, By5 = By4*cy;
            float wx4 = 0.f, wx5 = 0.f;
            #pragma unroll
            for (int i = 0; i < 8; ++i) {
                float cx = cx0 + 0.03125f*(float)i;
                float cx2 = cx*cx;
                float b4 = exq[i]*cx2*cx2;          // ex*cx^4
                wx4 += vr[i]*b4; wx5 += vr[i]*b4*cx;
            }
            float acc3[16];
            #pragma unroll
            for (int q = 0; q < 4; ++q) { acc3[q] = By4*wx[q]; acc3[4+q] = By5*wx[q]; }
            #pragma unroll
            for (int p = 0; p < 4; ++p) { acc3[8+p*2] = By[p]*wx4; acc3[8+p*2+1] = By[p]*wx5; }
            float red3 = reduce16(acc3, lane);
            if (lane < 16) atomicAdd(&EXTb[brl], red3);
        }
        __syncthreads();                               // B3/B5
    }
    // Final raw S core lives in Sb[SFINAL]; EXTb complete.
    const int SFINAL = ((NITER-1)&1)^1;

    // ---- merged stats + wd interval (wd reads cores from LDS) ----
    float part[10];
    {
        float Axe[6], Aye[6];
        mk6(xa, Axe); mk6(ya, Aye);
        float wdp = wd_point2(Axe, Aye, Axga, Ayga, ua, &Sb[SFINAL][0], EXTb);
        mk6(xb, Axe); mk6(yb, Aye);
        wdp += wd_point2(Axe, Aye, Axgb, Aygb, ub, &Sb[SFINAL][0], EXTb);
        part[9] = wdp;
    }
    {
        float4 ua4 = UDS[2*t], ub4 = UDS[2*t+1];
        float udr[8] = {ua4.x,ua4.y,ua4.z,ua4.w, ub4.x,ub4.y,ub4.z,ub4.w};
        float4 va4 = VPS[2*t], vb4 = VPS[2*t+1];
        float vpr[8] = {va4.x,va4.y,va4.z,va4.w, vb4.x,vb4.y,vb4.z,vb4.w};
        float nb=0.f, sud=0.f, sudb=0.f, svpv=0.f, svpvp=0.f, svv=0.f;
        #pragma unroll
        for (int i = 0; i < 8; ++i) {
            float beta = 10.0f*__logf(vr[i] + 1e-16f);
            nb    += br[i]*beta;
            sud   += udr[i];
            sudb  += udr[i]*beta;
            svpv  += vpr[i]*vr[i];
            svpvp += vpr[i]*vpr[i];
            svv   += vr[i]*vr[i];
        }
        part[0] = nb;    part[1] = sud;   part[2] = sudb;  part[3] = svpv;
        part[4] = svpvp; part[5] = svv;
        part[6] = upa*ua + upb*ub;
        part[7] = upa*upa + upb*upb;
        part[8] = ua*ua + ub*ub;
    }
    #pragma unroll
    for (int off = 32; off > 0; off >>= 1) {
        #pragma unroll
        for (int i = 0; i < 10; ++i) part[i] += __shfl_down(part[i], off);
    }
    if (lane == 0) {
        #pragma unroll
        for (int i = 0; i < 10; ++i) REDD[wv][i] = part[i];
    }
    __syncthreads();                                   // B6
    if (t == 0) {
        float P[10];
        #pragma unroll
        for (int i = 0; i < 10; ++i) {
            float s = 0.f;
            for (int w = 0; w < 8; ++w) s += REDD[w][i];
            P[i] = s;
        }
        float sc = P[1], Sbt = P[2];
        float denom = sc*sc + 1e-8f;
        float loss_pre = (sc/denom)*Sbt - (Sbt/denom)*sc;   // == sum(ud*im_grad) ~ 0
        float nvp = fmaxf(sqrtf(P[4]), 1e-8f);
        float nv  = fmaxf(sqrtf(P[5]), 1e-8f);
        float c1  = P[3]/(nvp*nv);
        float nup = fmaxf(sqrtf(P[7]), 1e-8f);
        float nu  = fmaxf(sqrtf(P[8]), 1e-8f);
        float c2  = P[6]/(nup*nu);
        float loss_i = loss_pre + (1.0f - c1) + (1.0f - c2);

        // graph memset re-zeros d_out each replay; fp-ordering jitter ~1e-6
        atomicAdd(&out[0], loss_i);
        atomicAdd(&out[1], P[9]);    // wd_i
        atomicAdd(&out[2], P[0]);    // ot_i
    }
}

extern "C" void kernel_launch(void* const* d_in, const int* in_sizes, int n_in,
                              void* d_out, int out_size, void* d_ws, size_t ws_size,
                              hipStream_t stream) {
    const float* nd  = (const float*)d_in[0];
    const float* ud  = (const float*)d_in[1];
    const float* pts = (const float*)d_in[2];
    const float* vp  = (const float*)d_in[3];
    float* out = (float*)d_out;

    hipMemsetAsync(out, 0, 3*sizeof(float), stream);   // graph-safe memset node
    ot_main<<<dim3(8), dim3(512), 0, stream>>>(nd, ud, pts, vp, out);
}